// Round 5
// baseline (196.238 us; speedup 1.0000x reference)
//
#include <hip/hip_runtime.h>
#include <math.h>

#define NGRAPH 256
#define LNODE  64
#define HEADS  8
#define DIN    512
#define EPG    256   // edges per graph
#define NEDGE  65536

__device__ __forceinline__ float softplusf(float v) {
    return (v > 20.f) ? v : log1pf(expf(v));
}
__device__ __forceinline__ unsigned short f2bf(float f) {   // RNE f32 -> bf16
    union { float f; unsigned u; } c; c.f = f;
    unsigned r = c.u + 0x7fffu + ((c.u >> 16) & 1u);
    return (unsigned short)(r >> 16);
}
__device__ __forceinline__ float bf2f(unsigned short h) {
    union { float f; unsigned u; } c; c.u = ((unsigned)h) << 16;
    return c.f;
}
__device__ __forceinline__ unsigned packbf2(float a, float b) {  // lo=a, hi=b
    return (unsigned)f2bf(a) | (((unsigned)f2bf(b)) << 16);
}

// ---------------- K1: CB partials. tposed=0 -> CBp[s][b][i][t] ; tposed=1 -> [s][b][t][i]
__global__ __launch_bounds__(256) void cb_kernel(const float* __restrict__ Bm,
                                                 const float* __restrict__ Cm,
                                                 float* __restrict__ CBp,
                                                 int dper, int tposed) {
    int b = blockIdx.x;
    int slice = blockIdx.y;
    __shared__ float Cs[64 * 68];
    __shared__ float Bs[64 * 68];
    int tid = threadIdx.x;
    int ti = tid >> 4, tj = tid & 15;
    float acc[4][4] = {};
    const float* Cg = Cm + (size_t)b * 64 * DIN;
    const float* Bg = Bm + (size_t)b * 64 * DIN;
    int d_lo = slice * dper;
    for (int d0 = d_lo; d0 < d_lo + dper; d0 += 64) {
        __syncthreads();
        #pragma unroll
        for (int k = 0; k < 4; ++k) {
            int f = k * 256 + tid;
            int row = f >> 4;
            int c4 = (f & 15) << 2;
            *(float4*)(Cs + row * 68 + c4) = *(const float4*)(Cg + row * DIN + d0 + c4);
            *(float4*)(Bs + row * 68 + c4) = *(const float4*)(Bg + row * DIN + d0 + c4);
        }
        __syncthreads();
        for (int d = 0; d < 64; d += 4) {
            float4 cr[4], br[4];
            #pragma unroll
            for (int r = 0; r < 4; ++r) cr[r] = *(const float4*)(Cs + (4 * ti + r) * 68 + d);
            #pragma unroll
            for (int c = 0; c < 4; ++c) br[c] = *(const float4*)(Bs + (4 * tj + c) * 68 + d);
            #pragma unroll
            for (int r = 0; r < 4; ++r)
                #pragma unroll
                for (int c = 0; c < 4; ++c)
                    acc[r][c] += cr[r].x * br[c].x + cr[r].y * br[c].y +
                                 cr[r].z * br[c].z + cr[r].w * br[c].w;
        }
    }
    float* outp = CBp + ((size_t)slice * NGRAPH + b) * 4096;
    if (!tposed) {
        #pragma unroll
        for (int r = 0; r < 4; ++r)
            *(float4*)(outp + (4 * ti + r) * 64 + 4 * tj) =
                make_float4(acc[r][0], acc[r][1], acc[r][2], acc[r][3]);
    } else {
        #pragma unroll
        for (int r = 0; r < 4; ++r)
            #pragma unroll
            for (int c = 0; c < 4; ++c)
                outp[(4 * tj + c) * 64 + (4 * ti + r)] = acc[r][c];
    }
}

// ---------------- K2: prep. One block per (graph, head-quad). Wave w -> head hq*4+w.
// Produces W^T (bf16) with D folded into the diagonal: Wtg[gh][t][i].
__global__ __launch_bounds__(256) void prep_kernel(const float* __restrict__ dt,
                                                   const float* __restrict__ dt_edge,
                                                   const float* __restrict__ dt_bias,
                                                   const float* __restrict__ Dp,
                                                   const float* __restrict__ dag_masks,
                                                   const int* __restrict__ edge_index,
                                                   const float* __restrict__ CBp,
                                                   unsigned short* __restrict__ Wtg,
                                                   int nslice) {
    int b = blockIdx.x;
    int hq = blockIdx.y;                 // 0,1
    int tid = threadIdx.x;
    int w = tid >> 6;                    // wave 0..3
    int lane = tid & 63;
    int head = hq * 4 + w;

    __shared__ float CBsh[4096];                 // CB[i][t], 16 KB, shared by all waves
    __shared__ unsigned short Wt[4][4096];       // per-wave W^T rows, xor-swizzled 8-blocks
    __shared__ float Ab[4][512];
    __shared__ float dnsh[4][64];
    __shared__ float dts[4][64];
    __shared__ float dtt[4][64];
    __shared__ float ecsh[4][64];

    // stage CB (sum slices), cooperative
    for (int s4 = tid; s4 < 1024; s4 += 256) {
        float4 v = make_float4(0.f, 0.f, 0.f, 0.f);
        for (int s = 0; s < nslice; ++s) {
            float4 p = *(const float4*)(CBp + ((size_t)s * NGRAPH + b) * 4096 + s4 * 4);
            v.x += p.x; v.y += p.y; v.z += p.z; v.w += p.w;
        }
        *(float4*)(CBsh + s4 * 4) = v;
    }
    // wave-local init
    #pragma unroll
    for (int k = 0; k < 8; ++k) Ab[w][k * 64 + lane] = 0.f;
    dnsh[w][lane] = 0.f;
    ecsh[w][lane] = 0.f;
    float bias = dt_bias[head];
    {
        int node = b * 64 + lane;
        dts[w][lane] = softplusf(dt[node * 16 + head * 2 + 0] + bias);
        dtt[w][lane] = softplusf(dt[node * 16 + head * 2 + 1] + bias);
    }
    __syncthreads();   // CBsh visible to all; wave-local arrays ready

    // edge scatter (wave-local)
    #pragma unroll
    for (int k = 0; k < 4; ++k) {
        int e = b * EPG + k * 64 + lane;
        int sl = edge_index[e] & 63;
        int dl = edge_index[NEDGE + e] & 63;
        float m = dag_masks[e];
        float de = softplusf(dt_edge[e * HEADS + head] + bias);
        float dsum = (dts[w][sl] + dtt[w][dl] + de) * 0.57735026918962576451f;
        float dexp = expf(-dsum);
        atomicAdd(&Ab[w][dl * 8 + (dl - sl)], dexp * m);
        atomicAdd(&dnsh[w][dl], dsum * m);
        atomicAdd(&ecsh[w][dl], m);
    }

    // normalize band (lane = row i), wave-local ordering guarantees suffice
    {
        float eci = ecsh[w][lane];
        #pragma unroll
        for (int d = 1; d < 8; ++d) {
            int s_ = lane - d;
            if (s_ >= 0) {
                float den = sqrtf(eci * ecsh[w][s_]);
                if (den < 1.f) den = 1.f;
                Ab[w][lane * 8 + d] = Ab[w][lane * 8 + d] / den;
            }
        }
    }

    // solve + W^T emit. Lane j = column j = W^T row j. D folded on diagonal.
    {
        int j = lane;
        float Dh = Dp[head];
        float mwin[7] = {0.f, 0.f, 0.f, 0.f, 0.f, 0.f, 0.f};
        for (int i8 = 0; i8 < 8; ++i8) {
            unsigned pk[4];
            #pragma unroll
            for (int u = 0; u < 8; ++u) {
                int i = i8 * 8 + u;
                float mi = (j == i) ? 1.f : 0.f;
                #pragma unroll
                for (int s = 0; s < 7; ++s) mi += Ab[w][i * 8 + s + 1] * mwin[s];
                float wv = mi * CBsh[i * 64 + j] * dnsh[w][i];
                if (j == i) wv += Dh;
                #pragma unroll
                for (int s = 6; s > 0; --s) mwin[s] = mwin[s - 1];
                mwin[0] = mi;
                unsigned short hb = f2bf(wv);
                if (u & 1) pk[u >> 1] |= ((unsigned)hb) << 16;
                else       pk[u >> 1] = (unsigned)hb;
            }
            int cblk = i8 ^ (j & 7);     // xor swizzle: balanced banks on write & read
            *(uint4*)(&Wt[w][j * 64 + cblk * 8]) = make_uint4(pk[0], pk[1], pk[2], pk[3]);
        }
    }
    __syncthreads();

    // coalesced writeout of this wave's W^T (8 KB): 8 rows per instr
    {
        size_t ghbase = ((size_t)b * HEADS + head) * 4096;
        int r_off = lane >> 3;
        int ibk = lane & 7;
        #pragma unroll
        for (int r0 = 0; r0 < 64; r0 += 8) {
            int r = r0 + r_off;
            int cblk = ibk ^ (r & 7);
            uint4 v = *(const uint4*)(&Wt[w][r * 64 + cblk * 8]);
            *(uint4*)(Wtg + ghbase + (size_t)r * 64 + ibk * 8) = v;
        }
    }
}

// ---------------- K3: y[i][e] = sum_t W[i][t] X[t][e]; W^T bf16 from ws, X staged bf16
__global__ __launch_bounds__(256) void gemm_kernel(const float* __restrict__ x,
                                                   const unsigned short* __restrict__ Wtg,
                                                   float* __restrict__ out) {
    int b = blockIdx.x;
    int head = blockIdx.y;
    __shared__ unsigned short Wt[64 * 72];   // [t][i], stride 72 (b128-aligned, bank-balanced)
    __shared__ unsigned short Xs[64 * 72];   // [t][e] bf16, stride 72
    int tid = threadIdx.x;

    const uint4* wg = (const uint4*)(Wtg + ((size_t)b * HEADS + head) * 4096);
    #pragma unroll
    for (int q = 0; q < 2; ++q) {
        int s = q * 256 + tid;               // 512 uint4 slots
        int row = s >> 3;
        int c8 = (s & 7) * 8;
        *(uint4*)(&Wt[row * 72 + c8]) = wg[s];
    }
    const float* xg0 = x + (size_t)b * 64 * DIN + head * 64;
    #pragma unroll
    for (int k = 0; k < 4; ++k) {
        int s = k * 256 + tid;
        int row = s >> 4;
        int c4 = (s & 15) << 2;
        float4 v = *(const float4*)(xg0 + (size_t)row * DIN + c4);
        uint2 p = make_uint2(packbf2(v.x, v.y), packbf2(v.z, v.w));
        *(uint2*)(&Xs[row * 72 + c4]) = p;
    }
    __syncthreads();

    int ti = tid >> 4, tj = tid & 15;
    float acc[4][4] = {};
    #pragma unroll 4
    for (int t = 0; t < 64; ++t) {
        uint2 wp = *(const uint2*)(&Wt[t * 72 + 4 * ti]);   // broadcast (16 lanes/addr)
        float w0 = bf2f((unsigned short)(wp.x & 0xffffu));
        float w1 = bf2f((unsigned short)(wp.x >> 16));
        float w2 = bf2f((unsigned short)(wp.y & 0xffffu));
        float w3 = bf2f((unsigned short)(wp.y >> 16));
        uint2 xp = *(const uint2*)(&Xs[t * 72 + 4 * tj]);   // 16 addrs, conflict-free
        union { unsigned u; float f; } cx;
        float x0, x1, x2, x3;
        cx.u = xp.x << 16;          x0 = cx.f;
        cx.u = xp.x & 0xffff0000u;  x1 = cx.f;
        cx.u = xp.y << 16;          x2 = cx.f;
        cx.u = xp.y & 0xffff0000u;  x3 = cx.f;
        acc[0][0] += w0 * x0; acc[0][1] += w0 * x1; acc[0][2] += w0 * x2; acc[0][3] += w0 * x3;
        acc[1][0] += w1 * x0; acc[1][1] += w1 * x1; acc[1][2] += w1 * x2; acc[1][3] += w1 * x3;
        acc[2][0] += w2 * x0; acc[2][1] += w2 * x1; acc[2][2] += w2 * x2; acc[2][3] += w2 * x3;
        acc[3][0] += w3 * x0; acc[3][1] += w3 * x1; acc[3][2] += w3 * x2; acc[3][3] += w3 * x3;
    }
    #pragma unroll
    for (int r = 0; r < 4; ++r) {
        int i = 4 * ti + r;
        *(float4*)(out + ((size_t)(b * 64 + i)) * DIN + head * 64 + 4 * tj) =
            make_float4(acc[r][0], acc[r][1], acc[r][2], acc[r][3]);
    }
}

// ---------------- Fallback fused kernel (round-3 main) for small workspace ----------------
__global__ __launch_bounds__(256, 4) void fused_kernel(const float* __restrict__ x,
                                                       const float* __restrict__ dt,
                                                       const float* __restrict__ dt_edge,
                                                       const float* __restrict__ dt_bias,
                                                       const float* __restrict__ Dp,
                                                       const float* __restrict__ dag_masks,
                                                       const int* __restrict__ edge_index,
                                                       const float* __restrict__ CBt,
                                                       float* __restrict__ out,
                                                       int nslice) {
    int b = blockIdx.x;
    int head = blockIdx.y;
    __shared__ float Ab[64 * 8];
    __shared__ float Mt[64 * 68];
    __shared__ float Xs[64 * 64];
    __shared__ float dnsh[64];
    __shared__ float ecsh[64];
    __shared__ float dts[64];
    __shared__ float dtt[64];
    int tid = threadIdx.x;

    int t4 = tid >> 2;
    int ib = (tid & 3) << 4;
    float4 cbsum[4];
    #pragma unroll
    for (int g = 0; g < 4; ++g) cbsum[g] = make_float4(0.f, 0.f, 0.f, 0.f);
    for (int s = 0; s < nslice; ++s) {
        const float* p = CBt + ((size_t)s * NGRAPH + b) * 4096 + t4 * 64 + ib;
        #pragma unroll
        for (int g = 0; g < 4; ++g) {
            float4 v = *(const float4*)(p + 4 * g);
            cbsum[g].x += v.x; cbsum[g].y += v.y; cbsum[g].z += v.z; cbsum[g].w += v.w;
        }
    }
    const float* xg0 = x + ((size_t)b * 64) * DIN + head * 64;
    #pragma unroll
    for (int k = 0; k < 4; ++k) {
        int s = k * 256 + tid;
        int row = s >> 4;
        int c4 = (s & 15) << 2;
        *(float4*)(Xs + row * 64 + c4) = *(const float4*)(xg0 + (size_t)row * DIN + c4);
    }
    for (int k = tid; k < 512; k += 256) Ab[k] = 0.f;
    float bias = dt_bias[head];
    if (tid < 64) {
        dnsh[tid] = 0.f;
        ecsh[tid] = 0.f;
        int node = b * 64 + tid;
        dts[tid] = softplusf(dt[node * 16 + head * 2 + 0] + bias);
        dtt[tid] = softplusf(dt[node * 16 + head * 2 + 1] + bias);
    }
    __syncthreads();
    {
        int e = b * EPG + tid;
        int sl = edge_index[e] & 63;
        int dl = edge_index[NEDGE + e] & 63;
        float m = dag_masks[e];
        float de = softplusf(dt_edge[e * HEADS + head] + bias);
        float dsum = (dts[sl] + dtt[dl] + de) * 0.57735026918962576451f;
        float dexp = expf(-dsum);
        atomicAdd(&Ab[dl * 8 + (dl - sl)], dexp * m);
        atomicAdd(&dnsh[dl], dsum * m);
        atomicAdd(&ecsh[dl], m);
    }
    __syncthreads();
    for (int k = tid; k < 512; k += 256) {
        int i = k >> 3, d = k & 7;
        int src = i - d;
        if (d >= 1 && src >= 0) {
            float den = sqrtf(ecsh[i] * ecsh[src]);
            if (den < 1.f) den = 1.f;
            Ab[k] = Ab[k] / den;
        }
    }
    __syncthreads();
    if (tid < 64) {
        int j = tid;
        float mwin[7] = {0.f, 0.f, 0.f, 0.f, 0.f, 0.f, 0.f};
        for (int i = 0; i < 64; ++i) {
            float mi = (j == i) ? 1.f : 0.f;
            #pragma unroll
            for (int s = 0; s < 7; ++s) mi += Ab[i * 8 + s + 1] * mwin[s];
            Mt[j * 65 + i] = mi;
            #pragma unroll
            for (int s = 6; s > 0; --s) mwin[s] = mwin[s - 1];
            mwin[0] = mi;
        }
    }
    __syncthreads();
    {
        float wv[16];
        #pragma unroll
        for (int g = 0; g < 4; ++g) {
            float4 dn4 = *(const float4*)(dnsh + ib + 4 * g);
            wv[4 * g + 0] = Mt[t4 * 65 + ib + 4 * g + 0] * cbsum[g].x * dn4.x;
            wv[4 * g + 1] = Mt[t4 * 65 + ib + 4 * g + 1] * cbsum[g].y * dn4.y;
            wv[4 * g + 2] = Mt[t4 * 65 + ib + 4 * g + 2] * cbsum[g].z * dn4.z;
            wv[4 * g + 3] = Mt[t4 * 65 + ib + 4 * g + 3] * cbsum[g].w * dn4.w;
        }
        __syncthreads();
        #pragma unroll
        for (int g = 0; g < 4; ++g)
            *(float4*)(Mt + t4 * 68 + ib + 4 * g) =
                make_float4(wv[4 * g + 0], wv[4 * g + 1], wv[4 * g + 2], wv[4 * g + 3]);
    }
    __syncthreads();
    int ti = tid >> 4, tj = tid & 15;
    float acc[4][4] = {};
    #pragma unroll 4
    for (int t = 0; t < 64; ++t) {
        float4 w4 = *(const float4*)(Mt + t * 68 + 4 * ti);
        float4 xv = *(const float4*)(Xs + t * 64 + 4 * tj);
        acc[0][0] += w4.x * xv.x; acc[0][1] += w4.x * xv.y; acc[0][2] += w4.x * xv.z; acc[0][3] += w4.x * xv.w;
        acc[1][0] += w4.y * xv.x; acc[1][1] += w4.y * xv.y; acc[1][2] += w4.y * xv.z; acc[1][3] += w4.y * xv.w;
        acc[2][0] += w4.z * xv.x; acc[2][1] += w4.z * xv.y; acc[2][2] += w4.z * xv.z; acc[2][3] += w4.z * xv.w;
        acc[3][0] += w4.w * xv.x; acc[3][1] += w4.w * xv.y; acc[3][2] += w4.w * xv.z; acc[3][3] += w4.w * xv.w;
    }
    float Dh = Dp[head];
    #pragma unroll
    for (int r = 0; r < 4; ++r) {
        int i = 4 * ti + r;
        float4 xres = *(const float4*)(Xs + i * 64 + 4 * tj);
        float4 v;
        v.x = acc[r][0] + xres.x * Dh;
        v.y = acc[r][1] + xres.y * Dh;
        v.z = acc[r][2] + xres.z * Dh;
        v.w = acc[r][3] + xres.w * Dh;
        *(float4*)(out + ((size_t)(b * 64 + i)) * DIN + head * 64 + 4 * tj) = v;
    }
}

extern "C" void kernel_launch(void* const* d_in, const int* in_sizes, int n_in,
                              void* d_out, int out_size, void* d_ws, size_t ws_size,
                              hipStream_t stream) {
    const float* x        = (const float*)d_in[0];
    const float* Bm       = (const float*)d_in[1];
    const float* Cm       = (const float*)d_in[2];
    const float* dt       = (const float*)d_in[3];
    const float* dt_edge  = (const float*)d_in[4];
    const float* dt_bias  = (const float*)d_in[5];
    const float* Dp       = (const float*)d_in[6];
    const float* dag_mask = (const float*)d_in[7];
    const int*   edge_idx = (const int*)d_in[8];
    float* out = (float*)d_out;

    const size_t CBSLICE = (size_t)NGRAPH * 4096 * 4;          // 4 MiB per slice
    const size_t WBYTES  = (size_t)NGRAPH * HEADS * 4096 * 2;  // 16 MiB bf16 W^T

    int nslice;
    bool fused;
    if (ws_size >= WBYTES + 2 * CBSLICE)      { fused = false; nslice = 2; }
    else if (ws_size >= WBYTES + 1 * CBSLICE) { fused = false; nslice = 1; }
    else { fused = true; nslice = (ws_size >= 4 * CBSLICE) ? 4 : 1; }

    float* CBp = (float*)d_ws;
    int dper = DIN / nslice;

    if (!fused) {
        unsigned short* Wtg = (unsigned short*)((char*)d_ws + nslice * CBSLICE);
        cb_kernel<<<dim3(NGRAPH, nslice), 256, 0, stream>>>(Bm, Cm, CBp, dper, 0);
        prep_kernel<<<dim3(NGRAPH, 2), 256, 0, stream>>>(dt, dt_edge, dt_bias, Dp,
                                                         dag_mask, edge_idx, CBp, Wtg, nslice);
        gemm_kernel<<<dim3(NGRAPH, HEADS), 256, 0, stream>>>(x, Wtg, out);
    } else {
        cb_kernel<<<dim3(NGRAPH, nslice), 256, 0, stream>>>(Bm, Cm, CBp, dper, 1);
        fused_kernel<<<dim3(NGRAPH, HEADS), 256, 0, stream>>>(x, dt, dt_edge, dt_bias, Dp,
                                                              dag_mask, edge_idx, CBp, out, nslice);
    }
}

// Round 6
// 192.723 us; speedup vs baseline: 1.0182x; 1.0182x over previous
//
#include <hip/hip_runtime.h>
#include <math.h>

#define NGRAPH 256
#define LNODE  64
#define HEADS  8
#define DIN    512
#define EPG    256   // edges per graph
#define NEDGE  65536

typedef short bf16x8 __attribute__((ext_vector_type(8)));
typedef float f32x4 __attribute__((ext_vector_type(4)));

__device__ __forceinline__ float softplusf(float v) {
    return (v > 20.f) ? v : log1pf(expf(v));
}
__device__ __forceinline__ unsigned short f2bf(float f) {   // RNE f32 -> bf16
    union { float f; unsigned u; } c; c.f = f;
    unsigned r = c.u + 0x7fffu + ((c.u >> 16) & 1u);
    return (unsigned short)(r >> 16);
}
__device__ __forceinline__ float bf2f(unsigned short h) {
    union { float f; unsigned u; } c; c.u = ((unsigned)h) << 16;
    return c.f;
}

// ---------------- K1: CB partials. tposed=0 -> CBp[s][b][i][t] ; tposed=1 -> [s][b][t][i]
__global__ __launch_bounds__(256) void cb_kernel(const float* __restrict__ Bm,
                                                 const float* __restrict__ Cm,
                                                 float* __restrict__ CBp,
                                                 int dper, int tposed) {
    int b = blockIdx.x;
    int slice = blockIdx.y;
    __shared__ float Cs[64 * 68];
    __shared__ float Bs[64 * 68];
    int tid = threadIdx.x;
    int ti = tid >> 4, tj = tid & 15;
    float acc[4][4] = {};
    const float* Cg = Cm + (size_t)b * 64 * DIN;
    const float* Bg = Bm + (size_t)b * 64 * DIN;
    int d_lo = slice * dper;
    for (int d0 = d_lo; d0 < d_lo + dper; d0 += 64) {
        __syncthreads();
        #pragma unroll
        for (int k = 0; k < 4; ++k) {
            int f = k * 256 + tid;
            int row = f >> 4;
            int c4 = (f & 15) << 2;
            *(float4*)(Cs + row * 68 + c4) = *(const float4*)(Cg + row * DIN + d0 + c4);
            *(float4*)(Bs + row * 68 + c4) = *(const float4*)(Bg + row * DIN + d0 + c4);
        }
        __syncthreads();
        for (int d = 0; d < 64; d += 4) {
            float4 cr[4], br[4];
            #pragma unroll
            for (int r = 0; r < 4; ++r) cr[r] = *(const float4*)(Cs + (4 * ti + r) * 68 + d);
            #pragma unroll
            for (int c = 0; c < 4; ++c) br[c] = *(const float4*)(Bs + (4 * tj + c) * 68 + d);
            #pragma unroll
            for (int r = 0; r < 4; ++r)
                #pragma unroll
                for (int c = 0; c < 4; ++c)
                    acc[r][c] += cr[r].x * br[c].x + cr[r].y * br[c].y +
                                 cr[r].z * br[c].z + cr[r].w * br[c].w;
        }
    }
    float* outp = CBp + ((size_t)slice * NGRAPH + b) * 4096;
    if (!tposed) {
        #pragma unroll
        for (int r = 0; r < 4; ++r)
            *(float4*)(outp + (4 * ti + r) * 64 + 4 * tj) =
                make_float4(acc[r][0], acc[r][1], acc[r][2], acc[r][3]);
    } else {
        #pragma unroll
        for (int r = 0; r < 4; ++r)
            #pragma unroll
            for (int c = 0; c < 4; ++c)
                outp[(4 * tj + c) * 64 + (4 * ti + r)] = acc[r][c];
    }
}

// ---------------- K2: fused solve + MFMA GEMM. One block per (graph, head). ----------------
// Phase 1: stage CB(bf16), Xt(bf16 transposed [e][t]), band scatter inputs.
// Phase 4: wave 0 solves (I-A)^-1 and emits W[i][t] bf16 (D on diagonal).
// Phase 5: 4 waves do y = W @ X via mfma_f32_16x16x32_bf16.
__global__ __launch_bounds__(256, 4) void fused2_kernel(const float* __restrict__ x,
                                                        const float* __restrict__ dt,
                                                        const float* __restrict__ dt_edge,
                                                        const float* __restrict__ dt_bias,
                                                        const float* __restrict__ Dp,
                                                        const float* __restrict__ dag_masks,
                                                        const int* __restrict__ edge_index,
                                                        const float* __restrict__ CBp,
                                                        float* __restrict__ out,
                                                        int nslice) {
    int b = blockIdx.x;
    int head = blockIdx.y;
    __shared__ unsigned short CBsh[64 * 64];  // CB[i][t] bf16, 8 KB
    __shared__ unsigned short Wl[64 * 72];    // W[i][t] bf16, stride 72 (16B-aligned rows)
    __shared__ unsigned short Xt[64 * 72];    // X^T[e][t] bf16, stride 72
    __shared__ float Ab[512];                 // band: Ab[i*8 + (i-src)], diff in [1,7]
    __shared__ float dnsh[64];
    __shared__ float ecsh[64];
    __shared__ float dts[64];
    __shared__ float dtt[64];
    int tid = threadIdx.x;
    int w = tid >> 6;
    int lane = tid & 63;

    // --- phase 1a: stage CB = sum slices -> bf16 LDS ---
    for (int s4 = tid; s4 < 1024; s4 += 256) {
        float4 v = make_float4(0.f, 0.f, 0.f, 0.f);
        for (int s = 0; s < nslice; ++s) {
            float4 p = *(const float4*)(CBp + ((size_t)s * NGRAPH + b) * 4096 + s4 * 4);
            v.x += p.x; v.y += p.y; v.z += p.z; v.w += p.w;
        }
        unsigned short* q = &CBsh[s4 * 4];
        q[0] = f2bf(v.x); q[1] = f2bf(v.y); q[2] = f2bf(v.z); q[3] = f2bf(v.w);
    }
    // --- phase 1b: X tile transposed -> Xt[e][t] bf16 ---
    const float* xg0 = x + (size_t)b * 64 * DIN + head * 64;
    #pragma unroll
    for (int k = 0; k < 4; ++k) {
        int s = k * 256 + tid;
        int t = s >> 4;
        int e0 = (s & 15) << 2;
        float4 v = *(const float4*)(xg0 + (size_t)t * DIN + e0);
        Xt[(e0 + 0) * 72 + t] = f2bf(v.x);
        Xt[(e0 + 1) * 72 + t] = f2bf(v.y);
        Xt[(e0 + 2) * 72 + t] = f2bf(v.z);
        Xt[(e0 + 3) * 72 + t] = f2bf(v.w);
    }
    // --- phase 1c: zero band + node softplus ---
    for (int k = tid; k < 512; k += 256) Ab[k] = 0.f;
    float bias = dt_bias[head];
    if (tid < 64) {
        dnsh[tid] = 0.f;
        ecsh[tid] = 0.f;
        int node = b * 64 + tid;
        dts[tid] = softplusf(dt[node * 16 + head * 2 + 0] + bias);
        dtt[tid] = softplusf(dt[node * 16 + head * 2 + 1] + bias);
    }
    __syncthreads();

    // --- phase 2: edge scatter into band ---
    {
        int e = b * EPG + tid;
        int sl = edge_index[e] & 63;
        int dl = edge_index[NEDGE + e] & 63;
        float mk = dag_masks[e];
        float de = softplusf(dt_edge[e * HEADS + head] + bias);
        float dsum = (dts[sl] + dtt[dl] + de) * 0.57735026918962576451f; // 1/sqrt(3)
        float dexp = expf(-dsum);
        atomicAdd(&Ab[dl * 8 + (dl - sl)], dexp * mk);
        atomicAdd(&dnsh[dl], dsum * mk);
        atomicAdd(&ecsh[dl], mk);
    }
    __syncthreads();

    // --- phase 3: normalize band ---
    for (int k = tid; k < 512; k += 256) {
        int i = k >> 3, d = k & 7;
        int src = i - d;
        if (d >= 1 && src >= 0) {
            float den = sqrtf(ecsh[i] * ecsh[src]);
            if (den < 1.f) den = 1.f;
            Ab[k] = Ab[k] / den;
        }
    }
    __syncthreads();

    // --- phase 4: wave 0 solves; lane j = column j. W[i][j] = M[i][j]*CB[i][j]*dn[i] (+D on diag) ---
    if (w == 0) {
        int j = lane;
        float Dh = Dp[head];
        float mwin[7] = {0.f, 0.f, 0.f, 0.f, 0.f, 0.f, 0.f};
        for (int i = 0; i < 64; ++i) {
            float mi = (j == i) ? 1.f : 0.f;
            #pragma unroll
            for (int s = 0; s < 7; ++s) mi += Ab[i * 8 + s + 1] * mwin[s];
            float wv = mi * bf2f(CBsh[i * 64 + j]) * dnsh[i];
            if (j == i) wv += Dh;
            Wl[i * 72 + j] = f2bf(wv);
            #pragma unroll
            for (int s = 6; s > 0; --s) mwin[s] = mwin[s - 1];
            mwin[0] = mi;
        }
    }
    __syncthreads();

    // --- phase 5: y[i][e] = sum_t W[i][t] X[t][e] via MFMA 16x16x32 bf16 ---
    // A-frag: lane holds A[m=lane&15][k=quad*8+j]; B-frag: B[k=quad*8+j][n=lane&15]=Xt[n][k].
    // C/D: col=lane&15, row=quad*4+reg.
    {
        int m = lane & 15;
        int quad = lane >> 4;
        bf16x8 a0 = *(const bf16x8*)(&Wl[(16 * w + m) * 72 + quad * 8]);
        bf16x8 a1 = *(const bf16x8*)(&Wl[(16 * w + m) * 72 + 32 + quad * 8]);
        float* og = out + ((size_t)b * 64) * DIN + head * 64;
        #pragma unroll
        for (int eb = 0; eb < 4; ++eb) {
            bf16x8 b0 = *(const bf16x8*)(&Xt[(eb * 16 + m) * 72 + quad * 8]);
            bf16x8 b1 = *(const bf16x8*)(&Xt[(eb * 16 + m) * 72 + 32 + quad * 8]);
            f32x4 acc = {0.f, 0.f, 0.f, 0.f};
            acc = __builtin_amdgcn_mfma_f32_16x16x32_bf16(a0, b0, acc, 0, 0, 0);
            acc = __builtin_amdgcn_mfma_f32_16x16x32_bf16(a1, b1, acc, 0, 0, 0);
            #pragma unroll
            for (int r = 0; r < 4; ++r) {
                int row = 16 * w + quad * 4 + r;
                og[(size_t)row * DIN + eb * 16 + m] = acc[r];
            }
        }
    }
}

// ---------------- Fallback fused kernel (round-3 main) for small workspace ----------------
__global__ __launch_bounds__(256, 4) void fused_kernel(const float* __restrict__ x,
                                                       const float* __restrict__ dt,
                                                       const float* __restrict__ dt_edge,
                                                       const float* __restrict__ dt_bias,
                                                       const float* __restrict__ Dp,
                                                       const float* __restrict__ dag_masks,
                                                       const int* __restrict__ edge_index,
                                                       const float* __restrict__ CBt,
                                                       float* __restrict__ out,
                                                       int nslice) {
    int b = blockIdx.x;
    int head = blockIdx.y;
    __shared__ float Ab[64 * 8];
    __shared__ float Mt[64 * 68];
    __shared__ float Xs[64 * 64];
    __shared__ float dnsh[64];
    __shared__ float ecsh[64];
    __shared__ float dts[64];
    __shared__ float dtt[64];
    int tid = threadIdx.x;

    int t4 = tid >> 2;
    int ib = (tid & 3) << 4;
    float4 cbsum[4];
    #pragma unroll
    for (int g = 0; g < 4; ++g) cbsum[g] = make_float4(0.f, 0.f, 0.f, 0.f);
    for (int s = 0; s < nslice; ++s) {
        const float* p = CBt + ((size_t)s * NGRAPH + b) * 4096 + t4 * 64 + ib;
        #pragma unroll
        for (int g = 0; g < 4; ++g) {
            float4 v = *(const float4*)(p + 4 * g);
            cbsum[g].x += v.x; cbsum[g].y += v.y; cbsum[g].z += v.z; cbsum[g].w += v.w;
        }
    }
    const float* xg0 = x + ((size_t)b * 64) * DIN + head * 64;
    #pragma unroll
    for (int k = 0; k < 4; ++k) {
        int s = k * 256 + tid;
        int row = s >> 4;
        int c4 = (s & 15) << 2;
        *(float4*)(Xs + row * 64 + c4) = *(const float4*)(xg0 + (size_t)row * DIN + c4);
    }
    for (int k = tid; k < 512; k += 256) Ab[k] = 0.f;
    float bias = dt_bias[head];
    if (tid < 64) {
        dnsh[tid] = 0.f;
        ecsh[tid] = 0.f;
        int node = b * 64 + tid;
        dts[tid] = softplusf(dt[node * 16 + head * 2 + 0] + bias);
        dtt[tid] = softplusf(dt[node * 16 + head * 2 + 1] + bias);
    }
    __syncthreads();
    {
        int e = b * EPG + tid;
        int sl = edge_index[e] & 63;
        int dl = edge_index[NEDGE + e] & 63;
        float mk = dag_masks[e];
        float de = softplusf(dt_edge[e * HEADS + head] + bias);
        float dsum = (dts[sl] + dtt[dl] + de) * 0.57735026918962576451f;
        float dexp = expf(-dsum);
        atomicAdd(&Ab[dl * 8 + (dl - sl)], dexp * mk);
        atomicAdd(&dnsh[dl], dsum * mk);
        atomicAdd(&ecsh[dl], mk);
    }
    __syncthreads();
    for (int k = tid; k < 512; k += 256) {
        int i = k >> 3, d = k & 7;
        int src = i - d;
        if (d >= 1 && src >= 0) {
            float den = sqrtf(ecsh[i] * ecsh[src]);
            if (den < 1.f) den = 1.f;
            Ab[k] = Ab[k] / den;
        }
    }
    __syncthreads();
    if (tid < 64) {
        int j = tid;
        float mwin[7] = {0.f, 0.f, 0.f, 0.f, 0.f, 0.f, 0.f};
        for (int i = 0; i < 64; ++i) {
            float mi = (j == i) ? 1.f : 0.f;
            #pragma unroll
            for (int s = 0; s < 7; ++s) mi += Ab[i * 8 + s + 1] * mwin[s];
            Mt[j * 65 + i] = mi;
            #pragma unroll
            for (int s = 6; s > 0; --s) mwin[s] = mwin[s - 1];
            mwin[0] = mi;
        }
    }
    __syncthreads();
    {
        float wv[16];
        #pragma unroll
        for (int g = 0; g < 4; ++g) {
            float4 dn4 = *(const float4*)(dnsh + ib + 4 * g);
            wv[4 * g + 0] = Mt[t4 * 65 + ib + 4 * g + 0] * cbsum[g].x * dn4.x;
            wv[4 * g + 1] = Mt[t4 * 65 + ib + 4 * g + 1] * cbsum[g].y * dn4.y;
            wv[4 * g + 2] = Mt[t4 * 65 + ib + 4 * g + 2] * cbsum[g].z * dn4.z;
            wv[4 * g + 3] = Mt[t4 * 65 + ib + 4 * g + 3] * cbsum[g].w * dn4.w;
        }
        __syncthreads();
        #pragma unroll
        for (int g = 0; g < 4; ++g)
            *(float4*)(Mt + t4 * 68 + ib + 4 * g) =
                make_float4(wv[4 * g + 0], wv[4 * g + 1], wv[4 * g + 2], wv[4 * g + 3]);
    }
    __syncthreads();
    int ti = tid >> 4, tj = tid & 15;
    float acc[4][4] = {};
    #pragma unroll 4
    for (int t = 0; t < 64; ++t) {
        float4 w4 = *(const float4*)(Mt + t * 68 + 4 * ti);
        float4 xv = *(const float4*)(Xs + t * 64 + 4 * tj);
        acc[0][0] += w4.x * xv.x; acc[0][1] += w4.x * xv.y; acc[0][2] += w4.x * xv.z; acc[0][3] += w4.x * xv.w;
        acc[1][0] += w4.y * xv.x; acc[1][1] += w4.y * xv.y; acc[1][2] += w4.y * xv.z; acc[1][3] += w4.y * xv.w;
        acc[2][0] += w4.z * xv.x; acc[2][1] += w4.z * xv.y; acc[2][2] += w4.z * xv.z; acc[2][3] += w4.z * xv.w;
        acc[3][0] += w4.w * xv.x; acc[3][1] += w4.w * xv.y; acc[3][2] += w4.w * xv.z; acc[3][3] += w4.w * xv.w;
    }
    float Dh = Dp[head];
    #pragma unroll
    for (int r = 0; r < 4; ++r) {
        int i = 4 * ti + r;
        float4 xres = *(const float4*)(Xs + i * 64 + 4 * tj);
        float4 v;
        v.x = acc[r][0] + xres.x * Dh;
        v.y = acc[r][1] + xres.y * Dh;
        v.z = acc[r][2] + xres.z * Dh;
        v.w = acc[r][3] + xres.w * Dh;
        *(float4*)(out + ((size_t)(b * 64 + i)) * DIN + head * 64 + 4 * tj) = v;
    }
}

extern "C" void kernel_launch(void* const* d_in, const int* in_sizes, int n_in,
                              void* d_out, int out_size, void* d_ws, size_t ws_size,
                              hipStream_t stream) {
    const float* x        = (const float*)d_in[0];
    const float* Bm       = (const float*)d_in[1];
    const float* Cm       = (const float*)d_in[2];
    const float* dt       = (const float*)d_in[3];
    const float* dt_edge  = (const float*)d_in[4];
    const float* dt_bias  = (const float*)d_in[5];
    const float* Dp       = (const float*)d_in[6];
    const float* dag_mask = (const float*)d_in[7];
    const int*   edge_idx = (const int*)d_in[8];
    float* out = (float*)d_out;

    const size_t CBSLICE = (size_t)NGRAPH * 4096 * 4;   // 4 MiB per slice
    float* CBp = (float*)d_ws;

    if (ws_size >= 2 * CBSLICE) {
        int nslice = 2;
        cb_kernel<<<dim3(NGRAPH, nslice), 256, 0, stream>>>(Bm, Cm, CBp, DIN / nslice, 0);
        fused2_kernel<<<dim3(NGRAPH, HEADS), 256, 0, stream>>>(x, dt, dt_edge, dt_bias, Dp,
                                                               dag_mask, edge_idx, CBp, out, nslice);
    } else {
        int nslice = 1;
        cb_kernel<<<dim3(NGRAPH, nslice), 256, 0, stream>>>(Bm, Cm, CBp, DIN / nslice, 1);
        fused_kernel<<<dim3(NGRAPH, HEADS), 256, 0, stream>>>(x, dt, dt_edge, dt_bias, Dp,
                                                              dag_mask, edge_idx, CBp, out, nslice);
    }
}